// Round 11
// baseline (137.116 us; speedup 1.0000x reference)
//
#include <hip/hip_runtime.h>

// Problem constants (fixed by setup_inputs): B=64, T=1024, V=128, S=256
constexpr int B_ = 64;
constexpr int T_ = 1024;
constexpr int V_ = 128;
constexpr int S_ = 256;
constexpr int GRING = 32;            // staged rows per direction (8 blocks of 4)
constexpr int ROWF = 384;            // floats per staged row: 3 planes x 64 lanes x float2
constexpr int NGW = 5;               // gather waves per direction
constexpr float INV_LN2 = 1.4426950408889634f;
constexpr float LN2 = 0.6931471805599453f;

#define WG_SCOPE __HIP_MEMORY_SCOPE_WORKGROUP

// DPP cross-lane move (VALU pipe — keeps the serial chain off the DS pipe).
// old=0, bound_ctrl=false: lanes with invalid source read 0.
template<int CTRL>
__device__ __forceinline__ float dppf(float x) {
    return __int_as_float(__builtin_amdgcn_update_dpp(
        0, __float_as_int(x), CTRL, 0xF, 0xF, false));
}
constexpr int DPP_WAVE_SHR1 = 0x138;   // lane i <- lane i-1 (lane 0 -> 0)
constexpr int DPP_WAVE_SHL1 = 0x130;   // lane i <- lane i+1 (lane 63 -> 0)
constexpr int DPP_ROW_SHR1  = 0x111;
constexpr int DPP_ROW_SHR2  = 0x112;
constexpr int DPP_ROW_SHR4  = 0x114;
constexpr int DPP_ROW_SHR8  = 0x118;
constexpr int DPP_BCAST15   = 0x142;
constexpr int DPP_BCAST31   = 0x143;

__device__ __forceinline__ void poll_eq(int* p, int want) {
    // RELAXED: producer's RELEASE store drained its ds_writes before the tag
    // became visible; ACQUIRE here would lgkmcnt(0)-drain our prefetch queue.
    while (__hip_atomic_load(p, __ATOMIC_RELAXED, WG_SCOPE) != want)
        __builtin_amdgcn_s_sleep(1);
}

// Wave-uniform rescale via DPP max-reduce (no DS pipe): pin wave max into
// [2^123, 2^124) — identical numerics to the R8/R10-proven butterfly scheme.
// Non-negative data => OOB-zero is the identity for max.
__device__ __forceinline__ int wave_rescale(float a[10], int& K) {
    float mx = a[0];
    #pragma unroll
    for (int k = 1; k < 10; ++k) mx = fmaxf(mx, a[k]);
    mx = fmaxf(mx, dppf<DPP_ROW_SHR1>(mx));
    mx = fmaxf(mx, dppf<DPP_ROW_SHR2>(mx));
    mx = fmaxf(mx, dppf<DPP_ROW_SHR4>(mx));
    mx = fmaxf(mx, dppf<DPP_ROW_SHR8>(mx));
    mx = fmaxf(mx, dppf<DPP_BCAST15>(mx));
    mx = fmaxf(mx, dppf<DPP_BCAST31>(mx));   // lane 63 = wave max
    const unsigned mb = (unsigned)__builtin_amdgcn_readlane(__float_as_uint(mx), 63);
    // mx = 1.m * 2^(E-127); ks = 250 - E pins max to [2^123, 2^124). mb==0 -> 0.
    const int ks = (mb != 0u) ? (250 - (int)(mb >> 23)) : 0;
    #pragma unroll
    for (int k = 0; k < 10; ++k) a[k] = ldexpf(a[k], ks);
    K += ks;
    return ks;
}

// Fused: 1 block / batch element. wave0 = forward alpha, wave1 = backward beta,
// waves 2..6 = fwd gatherers, 7..11 = bwd gatherers. Linear domain, wave-uniform K.
__global__ __launch_bounds__(768) void ctc_fused7(
    const float* __restrict__ lp,      // [B,T,V] natural-log softmax
    const int* __restrict__ in_len,    // [B]
    const int* __restrict__ tgt,       // [B,S]
    const int* __restrict__ tgt_len,   // [B]
    float* __restrict__ ws)            // [B] per-batch loss / L
{
    const int b    = blockIdx.x;
    const int tid  = threadIdx.x;
    const int wid  = tid >> 6;
    const int lane = tid & 63;

    __shared__ float ringF[GRING * ROWF];    // 48 KB
    __shared__ float ringB[GRING * ROWF];    // 48 KB
    __shared__ float dumpA[640];
    __shared__ float dumpB[640];
    __shared__ int   tagF[8], tagB[8];
    __shared__ int   consF, consB;
    __shared__ int   KFsh, KBsh;

    const int L  = tgt_len[b];        // 64..256
    const int Tb = in_len[b];         // 768..1024
    const float* lpb = lp + (size_t)b * T_ * V_;
    const int* tg = tgt + b * S_;

    const int tm = (Tb - 2) >> 1;
    const int Uf = tm;                // fwd steps: u=1..Uf (row t=u) -> alpha_tm
    const int Ub = Tb - 2 - tm;       // bwd steps: u=1..Ub (row t=Tb-1-u) -> g_{tm+1}

    if (tid == 0) { consF = 0; consB = 0; }
    if (tid < 8) tagF[tid] = -1;
    else if (tid < 16) tagB[tid - 8] = -1;
    __syncthreads();

    if (wid >= 2) {
        // ======================= gatherers =======================
        const int dir = (wid - 2) / NGW;           // 0 = fwd, 1 = bwd
        const int q   = (wid - 2) % NGW;
        const int U   = dir ? Ub : Uf;
        float* ring   = dir ? ringB : ringF;
        int*   tags   = dir ? tagB  : tagF;
        int*   consp  = dir ? &consB : &consF;

        int   labE[5];
        float vmask[5];
        #pragma unroll
        for (int c = 0; c < 5; ++c) {
            const int j = 5 * lane + c;
            if (j < L) { labE[c] = tg[j]; vmask[c] = 1.0f; }
            else       { labE[c] = 0;     vmask[c] = 0.0f; }
        }

        // block m covers rows u = 4m+1 .. 4m+4; row u lives at slot (u-1)&31
        for (int m = q; 4 * m + 1 <= U; m += NGW) {
            const int n = min(4, U - 4 * m);
            float v[4][6];
            #pragma unroll
            for (int r = 0; r < 4; ++r) {
                if (r < n) {
                    const int u = 4 * m + 1 + r;
                    const int t = dir ? (Tb - 1 - u) : u;
                    const float* row = lpb + (size_t)t * V_;
                    v[r][0] = row[0];
                    #pragma unroll
                    for (int c = 0; c < 5; ++c) v[r][c + 1] = row[labE[c]];
                }
            }
            // ring-slot reuse gate: slot shared with block m-8
            while (__hip_atomic_load(consp, __ATOMIC_RELAXED, WG_SCOPE) < 4 * m - 28)
                __builtin_amdgcn_s_sleep(1);
            #pragma unroll
            for (int r = 0; r < 4; ++r) {
                if (r < n) {
                    const int u = 4 * m + 1 + r;
                    float e[6];
                    e[0] = __builtin_exp2f(v[r][0] * INV_LN2);
                    #pragma unroll
                    for (int c = 0; c < 5; ++c)
                        e[c + 1] = vmask[c] * __builtin_exp2f(v[r][c + 1] * INV_LN2);
                    float* rb = ring + ((u - 1) & (GRING - 1)) * ROWF;
                    ((float2*)rb)[lane]         = make_float2(e[0], e[1]);
                    ((float2*)(rb + 128))[lane] = make_float2(e[2], e[3]);
                    ((float2*)(rb + 256))[lane] = make_float2(e[4], e[5]);
                }
            }
            if (lane == 0)
                __hip_atomic_store(&tags[m & 7], m, __ATOMIC_RELEASE, WG_SCOPE);
        }
    } else if (wid == 0) {
        // ======================= forward consumer =======================
        float skipf[5];
        #pragma unroll
        for (int c = 0; c < 5; ++c) {
            const int j = 5 * lane + c;
            skipf[c] = (j >= 1 && j < L && tg[j] != tg[j - 1]) ? 1.0f : 0.0f;
        }
        float a[10];
        #pragma unroll
        for (int k = 0; k < 10; ++k) a[k] = 0.0f;
        {
            const float p00 = __builtin_exp2f(lpb[0] * INV_LN2);
            const float p01 = __builtin_exp2f(lpb[tg[0]] * INV_LN2);
            if (lane == 0) { a[0] = p00; a[1] = p01; }
        }
        float u9n = 0.0f;                 // inflow alpha_prev[s-1] for s=10*lane
        int K = 0;

        float2 S[4][12];                  // [set][row*3+plane], all const-indexed
        auto readBlock = [&](int set, int m) {
            const int base = ((4 * m) & (GRING - 1)) * ROWF + 2 * lane;
            #pragma unroll
            for (int r = 0; r < 4; ++r)
                #pragma unroll
                for (int pl = 0; pl < 3; ++pl)
                    S[set][r * 3 + pl] =
                        *(const float2*)&ringF[base + r * ROWF + pl * 128];
        };
        auto rowCore = [&](float2 c0, float2 c1, float2 c2) {
            const float u9 = u9n;
            const float p0 = c0.x;
            a[9] = (a[9] + a[8] + skipf[4] * a[7]) * c2.y;
            u9n = dppf<DPP_WAVE_SHR1>(a[9]);   // early-produce; lane0 -> 0 free
            a[8] = (a[8] + a[7]) * p0;
            a[7] = (a[7] + a[6] + skipf[3] * a[5]) * c2.x;
            a[6] = (a[6] + a[5]) * p0;
            a[5] = (a[5] + a[4] + skipf[2] * a[3]) * c1.y;
            a[4] = (a[4] + a[3]) * p0;
            a[3] = (a[3] + a[2] + skipf[1] * a[1]) * c1.x;
            a[2] = (a[2] + a[1]) * p0;
            a[1] = (a[1] + a[0] + skipf[0] * u9) * c0.y;   // late-consume
            a[0] = (a[0] + u9) * p0;
        };
        auto row4 = [&](int set) {
            #pragma unroll
            for (int r = 0; r < 4; ++r)
                rowCore(S[set][r * 3], S[set][r * 3 + 1], S[set][r * 3 + 2]);
        };
        auto body = [&](int m, int setc, int setp) {
            if (4 * (m + 2) + 1 <= Uf) {
                poll_eq(&tagF[(m + 2) & 7], m + 2);
                readBlock(setp, m + 2);
            }
            row4(setc);
            if (lane == 0)
                __hip_atomic_store(&consF, 4 * m + 4, __ATOMIC_RELAXED, WG_SCOPE);
        };

        const int MB4 = (Uf / 4) & ~3;
        poll_eq(&tagF[0], 0); readBlock(0, 0);
        poll_eq(&tagF[1], 1); readBlock(1, 1);
        for (int mb = 0; mb < MB4; mb += 4) {
            body(mb + 0, 0, 2);
            body(mb + 1, 1, 3);
            { const int ks = wave_rescale(a, K); u9n = ldexpf(u9n, ks); }  // 8 rows
            body(mb + 2, 2, 0);
            body(mb + 3, 3, 1);
            { const int ks = wave_rescale(a, K); u9n = ldexpf(u9n, ks); }  // 8 rows
        }
        // tail: blocks MB4 (set0), MB4+1 (set1) partially, then direct ring rows
        #pragma unroll
        for (int r = 0; r < 4; ++r)
            if (4 * MB4 + 1 + r <= Uf)
                rowCore(S[0][r * 3], S[0][r * 3 + 1], S[0][r * 3 + 2]);
        #pragma unroll
        for (int r = 0; r < 4; ++r)
            if (4 * MB4 + 5 + r <= Uf)
                rowCore(S[1][r * 3], S[1][r * 3 + 1], S[1][r * 3 + 2]);
        { const int ks = wave_rescale(a, K); u9n = ldexpf(u9n, ks); }      // <=8 rows
        for (int u = 4 * MB4 + 9; u <= Uf; ++u) {                          // <=7 rows
            const int bu = (u - 1) >> 2;
            poll_eq(&tagF[bu & 7], bu);
            const int base = ((u - 1) & (GRING - 1)) * ROWF + 2 * lane;
            const float2 c0 = *(const float2*)&ringF[base];
            const float2 c1 = *(const float2*)&ringF[base + 128];
            const float2 c2 = *(const float2*)&ringF[base + 256];
            rowCore(c0, c1, c2);
        }

        #pragma unroll
        for (int k = 0; k < 10; ++k) dumpA[10 * lane + k] = a[k];
        if (lane == 0) {
            KFsh = K;
            __hip_atomic_store(&consF, Uf + 64, __ATOMIC_RELAXED, WG_SCOPE);
        }
    } else {
        // ======================= backward consumer =======================
        float sB[5];                  // skip into s+2 (odd): label j = 5*lane+c+1
        #pragma unroll
        for (int c = 0; c < 5; ++c) {
            const int j = 5 * lane + c + 1;
            sB[c] = (j < L && tg[j] != tg[j - 1]) ? 1.0f : 0.0f;
        }
        float g[10];
        #pragma unroll
        for (int k = 0; k < 10; ++k) g[k] = 0.0f;
        {   // g_{Tb-1}: nonzero at s=2L (blank) and s=2L-1 (last label)
            const float pb = __builtin_exp2f(lpb[(size_t)(Tb - 1) * V_] * INV_LN2);
            const float pl = __builtin_exp2f(lpb[(size_t)(Tb - 1) * V_ + tg[L - 1]] * INV_LN2);
            #pragma unroll
            for (int k = 0; k < 10; ++k) {
                const int s = 10 * lane + k;
                if (s == 2 * L)     g[k] = pb;
                if (s == 2 * L - 1) g[k] = pl;
            }
        }
        float d0n = dppf<DPP_WAVE_SHL1>(g[0]);   // lane63 -> 0 free
        float d1n = dppf<DPP_WAVE_SHL1>(g[1]);
        int K = 0;

        float2 S[4][12];
        auto readBlock = [&](int set, int m) {
            const int base = ((4 * m) & (GRING - 1)) * ROWF + 2 * lane;
            #pragma unroll
            for (int r = 0; r < 4; ++r)
                #pragma unroll
                for (int pl = 0; pl < 3; ++pl)
                    S[set][r * 3 + pl] =
                        *(const float2*)&ringB[base + r * ROWF + pl * 128];
        };
        auto rowCore = [&](float2 c0, float2 c1, float2 c2) {
            const float d0 = d0n, d1 = d1n;
            const float p0 = c0.x;
            g[0] = (g[0] + g[1]) * p0;
            g[1] = (g[1] + g[2] + sB[0] * g[3]) * c0.y;
            d0n = dppf<DPP_WAVE_SHL1>(g[0]);   // early-produce
            d1n = dppf<DPP_WAVE_SHL1>(g[1]);
            g[2] = (g[2] + g[3]) * p0;
            g[3] = (g[3] + g[4] + sB[1] * g[5]) * c1.x;
            g[4] = (g[4] + g[5]) * p0;
            g[5] = (g[5] + g[6] + sB[2] * g[7]) * c1.y;
            g[6] = (g[6] + g[7]) * p0;
            g[7] = (g[7] + g[8] + sB[3] * g[9]) * c2.x;
            g[8] = (g[8] + g[9]) * p0;
            g[9] = (g[9] + d0 + sB[4] * d1) * c2.y;      // late-consume
        };
        auto row4 = [&](int set) {
            #pragma unroll
            for (int r = 0; r < 4; ++r)
                rowCore(S[set][r * 3], S[set][r * 3 + 1], S[set][r * 3 + 2]);
        };
        auto body = [&](int m, int setc, int setp) {
            if (4 * (m + 2) + 1 <= Ub) {
                poll_eq(&tagB[(m + 2) & 7], m + 2);
                readBlock(setp, m + 2);
            }
            row4(setc);
            if (lane == 0)
                __hip_atomic_store(&consB, 4 * m + 4, __ATOMIC_RELAXED, WG_SCOPE);
        };

        const int MB4 = (Ub / 4) & ~3;
        poll_eq(&tagB[0], 0); readBlock(0, 0);
        poll_eq(&tagB[1], 1); readBlock(1, 1);
        for (int mb = 0; mb < MB4; mb += 4) {
            body(mb + 0, 0, 2);
            body(mb + 1, 1, 3);
            { const int ks = wave_rescale(g, K);
              d0n = ldexpf(d0n, ks); d1n = ldexpf(d1n, ks); }
            body(mb + 2, 2, 0);
            body(mb + 3, 3, 1);
            { const int ks = wave_rescale(g, K);
              d0n = ldexpf(d0n, ks); d1n = ldexpf(d1n, ks); }
        }
        #pragma unroll
        for (int r = 0; r < 4; ++r)
            if (4 * MB4 + 1 + r <= Ub)
                rowCore(S[0][r * 3], S[0][r * 3 + 1], S[0][r * 3 + 2]);
        #pragma unroll
        for (int r = 0; r < 4; ++r)
            if (4 * MB4 + 5 + r <= Ub)
                rowCore(S[1][r * 3], S[1][r * 3 + 1], S[1][r * 3 + 2]);
        { const int ks = wave_rescale(g, K);
          d0n = ldexpf(d0n, ks); d1n = ldexpf(d1n, ks); }
        for (int u = 4 * MB4 + 9; u <= Ub; ++u) {
            const int bu = (u - 1) >> 2;
            poll_eq(&tagB[bu & 7], bu);
            const int base = ((u - 1) & (GRING - 1)) * ROWF + 2 * lane;
            const float2 c0 = *(const float2*)&ringB[base];
            const float2 c1 = *(const float2*)&ringB[base + 128];
            const float2 c2 = *(const float2*)&ringB[base + 256];
            rowCore(c0, c1, c2);
        }

        {   // combine: gext[s] = g[s] + g[s+1] + skip[s+2]*g[s+2] (ascending)
            const float d0 = d0n, d1 = d1n;
            g[0] = g[0] + g[1];
            g[1] = g[1] + g[2] + sB[0] * g[3];
            g[2] = g[2] + g[3];
            g[3] = g[3] + g[4] + sB[1] * g[5];
            g[4] = g[4] + g[5];
            g[5] = g[5] + g[6] + sB[2] * g[7];
            g[6] = g[6] + g[7];
            g[7] = g[7] + g[8] + sB[3] * g[9];
            g[8] = g[8] + g[9];
            g[9] = g[9] + d0 + sB[4] * d1;
        }
        #pragma unroll
        for (int k = 0; k < 10; ++k) dumpB[10 * lane + k] = g[k];
        if (lane == 0) {
            KBsh = K;
            __hip_atomic_store(&consB, Ub + 64, __ATOMIC_RELAXED, WG_SCOPE);
        }
    }

    __syncthreads();
    if (wid == 0) {
        // join in DOUBLE (factors span ~240 bits in f32 frames — R7 lesson)
        double sum = 0.0;
        #pragma unroll
        for (int k = 0; k < 10; ++k)
            sum += (double)dumpA[10 * lane + k] * (double)dumpB[10 * lane + k];
        #pragma unroll
        for (int d = 1; d < 64; d <<= 1) sum += __shfl_xor(sum, d, 64);
        if (lane == 0) {
            float loss = 0.0f;                     // infeasible (sum<=0) -> 0
            if (sum > 0.0) {
                const long long ub = __double_as_longlong(sum);
                const int ex = (int)((ub >> 52) & 2047) - 1023;
                const double f = __longlong_as_double(
                    (ub & 0x000FFFFFFFFFFFFFLL) | 0x3FF0000000000000LL);
                const float ll2 = __builtin_log2f((float)f)
                                + (float)(ex - KFsh - KBsh);
                loss = -(ll2 * LN2);
                if (!(loss <= 1e29f)) loss = 0.0f; // zero_infinity
            }
            ws[b] = loss / (float)L;
        }
    }
}

__global__ void ctc_reduce_kernel(const float* __restrict__ ws, float* __restrict__ out) {
    float v = ws[threadIdx.x];
    #pragma unroll
    for (int o = 32; o > 0; o >>= 1) v += __shfl_down(v, o);
    if (threadIdx.x == 0) out[0] = v / (float)B_;
}

extern "C" void kernel_launch(void* const* d_in, const int* in_sizes, int n_in,
                              void* d_out, int out_size, void* d_ws, size_t ws_size,
                              hipStream_t stream) {
    const float* lp      = (const float*)d_in[0];
    const int*   in_len  = (const int*)d_in[1];
    const int*   tgt     = (const int*)d_in[2];
    const int*   tgt_len = (const int*)d_in[3];
    float* loss = (float*)d_ws;
    float* out  = (float*)d_out;

    ctc_fused7<<<B_, 768, 0, stream>>>(lp, in_len, tgt, tgt_len, loss);
    ctc_reduce_kernel<<<1, 64, 0, stream>>>(loss, out);
}